// Round 5
// baseline (481.521 us; speedup 1.0000x reference)
//
#include <hip/hip_runtime.h>
#include <hip/hip_bf16.h>
#include <cstdint>
#include <cstddef>

typedef unsigned short ushort_t;
typedef __bf16 bf16x8v __attribute__((ext_vector_type(8)));
typedef float f32x4 __attribute__((ext_vector_type(4)));

// Problem constants (from reference setup_inputs)
#define Bsz 4
#define Sseq 2048
#define Dd 1024
#define DFFd 4096
#define Ee 8
#define DFEd 1024
#define IDCUT 1024          // id = S//2
#define NTOK (Bsz*Sseq)     // 8192
#define NMOE (Bsz*(Sseq-IDCUT)) // 4096 MoE tokens
#define MAXSLOT 4096        // max slots per expert (observed ~1024, 4x headroom)

__device__ __forceinline__ ushort_t f2bf(float f) {
  unsigned u = __float_as_uint(f);
  u += 0x7fffu + ((u >> 16) & 1u);       // round-to-nearest-even
  return (ushort_t)(u >> 16);
}

__device__ __forceinline__ float gelu_tanh(float x) {
  float x3 = x * x * x;
  float t = tanhf(0.7978845608028654f * (x + 0.044715f * x3));
  return 0.5f * x * (1.0f + t);
}

__device__ __forceinline__ void gload_lds16(const void* g, void* l) {
  __builtin_amdgcn_global_load_lds(
      (const __attribute__((address_space(1))) void*)g,
      (__attribute__((address_space(3))) void*)l,
      16, 0, 0);
}

// ---------------- cast x fp32 -> bf16 (straight) ----------------
__global__ void cast4_k(const float* __restrict__ in, ushort_t* __restrict__ out, int n4) {
  int i = blockIdx.x * 256 + threadIdx.x;
  if (i >= n4) return;
  const float4 v = ((const float4*)in)[i];
  ushort4 o;
  o.x = f2bf(v.x); o.y = f2bf(v.y); o.z = f2bf(v.z); o.w = f2bf(v.w);
  ((ushort4*)out)[i] = o;
}

// ---------------- transpose-cast: in [R][C] fp32 -> out [C][R] bf16, batched over z ----------------
__global__ void tcast_k(const float* __restrict__ in, ushort_t* __restrict__ out, int R, int C) {
  __shared__ float tile[32][33];
  const size_t base = (size_t)blockIdx.z * (size_t)R * (size_t)C;
  in += base; out += base;
  int tx = threadIdx.x & 31, ty = threadIdx.x >> 5;   // 32 x 8
  int c = blockIdx.x * 32 + tx;
  #pragma unroll
  for (int i = 0; i < 32; i += 8) {
    int r = blockIdx.y * 32 + ty + i;
    tile[ty + i][tx] = in[(size_t)r * C + c];
  }
  __syncthreads();
  int rr = blockIdx.y * 32 + tx;
  #pragma unroll
  for (int i = 0; i < 32; i += 8) {
    int cc = blockIdx.x * 32 + ty + i;
    out[(size_t)cc * R + rr] = f2bf(tile[tx][ty + i]);
  }
}

// ---------------- router: top-2 gates + per-expert slot lists ----------------
__global__ void router_k(const float* __restrict__ x, const float* __restrict__ Wg,
                         int* __restrict__ cnt, int* __restrict__ slots,
                         float* __restrict__ gsv) {
  int t = blockIdx.x * 4 + (threadIdx.x >> 6);   // one wave per MoE token
  int lane = threadIdx.x & 63;
  int b = t >> 10;
  int s = (t & 1023) + IDCUT;
  const float* xr = x + ((size_t)b * Sseq + s) * Dd;
  float acc[8] = {0.f,0.f,0.f,0.f,0.f,0.f,0.f,0.f};
  for (int k = lane; k < Dd; k += 64) {
    float xv = xr[k];
    const float* wr = Wg + (size_t)k * Ee;
    #pragma unroll
    for (int e8 = 0; e8 < 8; ++e8) acc[e8] += xv * wr[e8];
  }
  #pragma unroll
  for (int off = 32; off > 0; off >>= 1) {
    #pragma unroll
    for (int e8 = 0; e8 < 8; ++e8) acc[e8] += __shfl_xor(acc[e8], off);
  }
  if (lane == 0) {
    int e0 = 0; float v0 = acc[0];
    #pragma unroll
    for (int e8 = 1; e8 < 8; ++e8) if (acc[e8] > v0) { v0 = acc[e8]; e0 = e8; }
    int e1 = -1; float v1 = -3.4e38f;
    #pragma unroll
    for (int e8 = 0; e8 < 8; ++e8) if (e8 != e0 && acc[e8] > v1) { v1 = acc[e8]; e1 = e8; }
    float g0 = 1.0f / (1.0f + expf(v1 - v0));   // = p0/(p0+p1), exact via softmax monotonicity
    float g1 = 1.0f - g0;
    int p0 = atomicAdd(&cnt[e0], 1);
    slots[e0 * MAXSLOT + p0] = t * 2;
    int p1 = atomicAdd(&cnt[e1], 1);
    slots[e1 * MAXSLOT + p1] = t * 2 + 1;
    gsv[t * 2] = g0;
    gsv[t * 2 + 1] = g1;
  }
}

// ================= 8-phase-class GEMM, snake quadrants (round 5) =================
// C[M,N] = A[M,K] * Bt[N,K]^T, BK=64, 8 waves, dbuf LDS, XOR-swizzled reads.
// Round-5 change: zero-re-read snake phase order (0,0)->(0,1)->(1,1)->(1,0):
// hold ALL B-frags + current A-half in regs; per-phase ds_reads {12,4,8,0}
// (was {12,12,12,12}) — per m201's "4 or 8 ds_read per phase". Top-of-iter
// vmcnt+barrier merged into phase 3 (8 barriers/K-tile).
// vmcnt ledger: ph3-end wait allows newest LA+LB (the t+2 A0/B0 stages) to
// float -> forces t+1's A1/B1 landed; t==NT-2 drains to 0 (epilogue rule).
// MODE 0: FFN1  A=xb direct,     epi: gelu(acc+b1)      -> bf16 h1
// MODE 1: FFN2  A=h1 direct,     epi: acc+b2            -> fp32 out
// MODE 2: MoE1  A=xb gathered,   epi: gelu(acc+be1[e])  -> bf16 h_slot[sv]
// MODE 3: MoE2  A=h_slot gather, epi: atomicAdd(out, LAM*gate*(acc+be2[e]))
template<int MODE, int BM_, int BN_, int WM_, int WN_>
__global__ __launch_bounds__(512, 2) void gemm8_k(
    const ushort_t* __restrict__ A,
    const ushort_t* __restrict__ Bt,
    const float* __restrict__ bias,
    void* __restrict__ C,
    int M, int K, int N, int NTX, int ldc,
    const int* __restrict__ cnt,
    const int* __restrict__ slots,
    const float* __restrict__ gates)
{
  constexpr int MFR = BM_ / WM_ / 16;       // A frags per wave
  constexpr int NFR = BN_ / WN_ / 16;       // B frags per wave
  constexpr int HA  = BM_ / (WM_ * 2);      // A half-granule rows
  constexpr int HB  = BN_ / (WN_ * 2);
  constexpr int LA  = (BM_ / 2) * 128 / 8192;  // global_load_lds per A-half (per thread-512)
  constexpr int LB  = (BN_ / 2) * 128 / 8192;
  constexpr int SZA = BM_ * 128;            // bytes, one buffer's A tile ([2 half][BM/2][128B])
  constexpr int SZB = BN_ * 128;
  constexpr int BUFS = SZA + SZB;
  constexpr int BMW = BM_ / WM_, BNW = BN_ / WN_;

  extern __shared__ char smem[];

  int nt, mt, e = 0;
  if (MODE < 2) {
    // bijective XCD swizzle (gridDim.x % 8 == 0 by construction)
    int wg = blockIdx.x;
    int cpx = gridDim.x >> 3;
    int swz = (wg & 7) * cpx + (wg >> 3);
    nt = swz % NTX; mt = swz / NTX;
  } else {
    nt = blockIdx.x; mt = blockIdx.y; e = blockIdx.z;
  }

  int rows = M;
  const int* slist = nullptr;
  if (MODE >= 2) {
    rows = cnt[e];
    if (mt * BM_ >= rows) return;
    slist = slots + e * MAXSLOT;
  }
  const ushort_t* Bte = (MODE >= 2) ? (Bt + (size_t)e * (size_t)K * (size_t)N) : Bt;
  const float* biase = (MODE >= 2) ? (bias + e * N) : bias;

  const int tid  = threadIdx.x;
  const int lane = tid & 63;
  const int wid  = tid >> 6;
  const int wm   = wid / WN_;
  const int wn   = wid % WN_;
  const int lr   = lane & 15;
  const int lg   = lane >> 4;
  const int swz7 = lane & 7;    // == row_local & 7 on the read side

  // --- staging source pointers (pre-swizzled global col so LDS dest stays linear) ---
  const ushort_t* gAp[2][LA];
  const ushort_t* gBp[2][LB];
  #pragma unroll
  for (int h = 0; h < 2; ++h) {
    #pragma unroll
    for (int j = 0; j < LA; ++j) {
      int tt = j * 512 + tid;
      int rl = tt >> 3, slot = tt & 7;
      int col8 = slot ^ (rl & 7);
      int r = (rl % HA) + ((rl / HA) * 2 + h) * HA;   // global row-in-tile for this half's slot
      int grow = mt * BM_ + r;
      size_t rowoff;
      if (MODE < 2) {
        rowoff = (size_t)grow;
      } else {
        int idx = grow > rows - 1 ? rows - 1 : grow;
        int sv = slist[idx];
        if (MODE == 2) { int t = sv >> 1; rowoff = (size_t)((t >> 10) * Sseq + IDCUT + (t & 1023)); }
        else           { rowoff = (size_t)sv; }
      }
      gAp[h][j] = A + rowoff * (size_t)K + col8 * 8;
    }
    #pragma unroll
    for (int j = 0; j < LB; ++j) {
      int tt = j * 512 + tid;
      int rl = tt >> 3, slot = tt & 7;
      int col8 = slot ^ (rl & 7);
      int rB = (rl % HB) + ((rl / HB) * 2 + h) * HB;
      gBp[h][j] = Bte + (size_t)(nt * BN_ + rB) * (size_t)K + col8 * 8;
    }
  }

  #define STAGE_A(h, bf, tk) do { \
    _Pragma("unroll") \
    for (int j = 0; j < LA; ++j) \
      gload_lds16(gAp[h][j] + (size_t)(tk) * 64, \
                  (void*)(smem + (bf) * BUFS + (h) * (SZA/2) + (j * 512 + wid * 64) * 16)); \
  } while (0)
  #define STAGE_B(h, bf, tk) do { \
    _Pragma("unroll") \
    for (int j = 0; j < LB; ++j) \
      gload_lds16(gBp[h][j] + (size_t)(tk) * 64, \
                  (void*)(smem + (bf) * BUFS + SZA + (h) * (SZB/2) + (j * 512 + wid * 64) * 16)); \
  } while (0)
  #define MFMA_QUAD(MH, NH) do { \
    _Pragma("unroll") \
    for (int q = 0; q < 2; ++q) \
      _Pragma("unroll") \
      for (int mi = 0; mi < MFR / 2; ++mi) \
        _Pragma("unroll") \
        for (int ni = 0; ni < NFR / 2; ++ni) \
          acc[(MH) * (MFR / 2) + mi][(NH) * (NFR / 2) + ni] = \
            __builtin_amdgcn_mfma_f32_16x16x32_bf16(av[mi][q], bv[(NH) * (NFR / 2) + ni][q], \
                acc[(MH) * (MFR / 2) + mi][(NH) * (NFR / 2) + ni], 0, 0, 0); \
  } while (0)
  #define PH_SYNC_MFMA(MH, NH) do { \
    __builtin_amdgcn_s_barrier(); \
    asm volatile("s_waitcnt lgkmcnt(0)" ::: "memory"); \
    __builtin_amdgcn_sched_barrier(0); \
    __builtin_amdgcn_s_setprio(1); \
    MFMA_QUAD(MH, NH); \
    __builtin_amdgcn_s_setprio(0); \
  } while (0)

  f32x4 acc[MFR][NFR];
  const f32x4 vzero = {0.f, 0.f, 0.f, 0.f};
  #pragma unroll
  for (int m = 0; m < MFR; ++m)
    #pragma unroll
    for (int n = 0; n < NFR; ++n) acc[m][n] = vzero;

  // --- precomputed per-lane swizzled LDS read offsets ---
  const unsigned aOff0 = (unsigned)((wm * HA + lr) * 128 + ((lg ^ swz7) << 4));
  const unsigned aOff1 = (unsigned)((wm * HA + lr) * 128 + (((4 + lg) ^ swz7) << 4));
  const unsigned bOff0 = (unsigned)(SZA + (wn * HB + lr) * 128 + ((lg ^ swz7) << 4));
  const unsigned bOff1 = (unsigned)(SZA + (wn * HB + lr) * 128 + (((4 + lg) ^ swz7) << 4));

  const int NT = K >> 6;

  // prologue: emulate issues of iterations -2,-1; then gate on t=0's A1/B1.
  STAGE_A(0, 0, 0); STAGE_B(0, 0, 0); STAGE_B(1, 0, 0); STAGE_A(1, 0, 0);
  if (NT > 1) { STAGE_A(0, 1, 1); STAGE_B(0, 1, 1); }
  if (NT > 1) {
    if constexpr (LA + LB == 4)      asm volatile("s_waitcnt vmcnt(4)" ::: "memory");
    else if constexpr (LA + LB == 3) asm volatile("s_waitcnt vmcnt(3)" ::: "memory");
    else                             asm volatile("s_waitcnt vmcnt(0)" ::: "memory");
  } else {
    asm volatile("s_waitcnt vmcnt(0)" ::: "memory");
  }
  __builtin_amdgcn_s_barrier();

  for (int t = 0; t < NT; ++t) {
    const int buf = t & 1;
    const char* aB0 = smem + buf * BUFS + aOff0;
    const char* aB1 = smem + buf * BUFS + aOff1;
    const char* bB0 = smem + buf * BUFS + bOff0;
    const char* bB1 = smem + buf * BUFS + bOff1;

    bf16x8v av[MFR / 2][2];   // current A-half (reused for both halves)
    bf16x8v bv[NFR][2];       // ALL B-frags held across the K-tile

    // ---- phase 0: quadrant (0,0); read A-half0 + B-half0 ----
    if (t + 1 < NT) STAGE_B(1, buf ^ 1, t + 1);
    #pragma unroll
    for (int mi = 0; mi < MFR / 2; ++mi) {
      av[mi][0] = *(const bf16x8v*)(aB0 + mi * 2048);
      av[mi][1] = *(const bf16x8v*)(aB1 + mi * 2048);
    }
    #pragma unroll
    for (int ni = 0; ni < NFR / 2; ++ni) {
      bv[ni][0] = *(const bf16x8v*)(bB0 + ni * 2048);
      bv[ni][1] = *(const bf16x8v*)(bB1 + ni * 2048);
    }
    PH_SYNC_MFMA(0, 0);
    __builtin_amdgcn_s_barrier();

    // ---- phase 1: quadrant (0,1); read B-half1 (A-half0 reused) ----
    if (t + 1 < NT) STAGE_A(1, buf ^ 1, t + 1);
    #pragma unroll
    for (int ni = 0; ni < NFR / 2; ++ni) {
      bv[NFR / 2 + ni][0] = *(const bf16x8v*)(bB0 + (SZB / 2 + ni * 2048));
      bv[NFR / 2 + ni][1] = *(const bf16x8v*)(bB1 + (SZB / 2 + ni * 2048));
    }
    PH_SYNC_MFMA(0, 1);
    __builtin_amdgcn_s_barrier();

    // ---- phase 2: quadrant (1,1); read A-half1 (B-half1 reused) ----
    if (t + 2 < NT) STAGE_A(0, buf, t + 2);
    #pragma unroll
    for (int mi = 0; mi < MFR / 2; ++mi) {
      av[mi][0] = *(const bf16x8v*)(aB0 + (SZA / 2 + mi * 2048));
      av[mi][1] = *(const bf16x8v*)(aB1 + (SZA / 2 + mi * 2048));
    }
    PH_SYNC_MFMA(1, 1);
    __builtin_amdgcn_s_barrier();

    // ---- phase 3: quadrant (1,0); no reads (A-half1 + B-half0 in regs) ----
    if (t + 2 < NT) STAGE_B(0, buf, t + 2);
    PH_SYNC_MFMA(1, 0);
    // merged end-of-iteration vmcnt (guards next iter's reads of buf^1)
    if (t < NT - 1) {
      if (t == NT - 2) {
        asm volatile("s_waitcnt vmcnt(0)" ::: "memory");
      } else {
        if constexpr (LA + LB == 4)      asm volatile("s_waitcnt vmcnt(4)" ::: "memory");
        else if constexpr (LA + LB == 3) asm volatile("s_waitcnt vmcnt(3)" ::: "memory");
        else                             asm volatile("s_waitcnt vmcnt(0)" ::: "memory");
      }
    }
    __builtin_amdgcn_s_barrier();
  }

  // --- epilogue: C/D layout col = lane&15, row = (lane>>4)*4 + jj ---
  #pragma unroll
  for (int mf = 0; mf < MFR; ++mf) {
    #pragma unroll
    for (int jj = 0; jj < 4; ++jj) {
      const int lrow = wm * BMW + mf * 16 + lg * 4 + jj;
      const int grow = mt * BM_ + lrow;
      size_t crow; float gt = 0.f;
      if (MODE >= 2) {
        if (grow >= rows) continue;
        int sv = slist[grow];
        if (MODE == 3) {
          gt = gates[sv];
          int tkn = sv >> 1;
          crow = (size_t)((tkn >> 10) * Sseq + IDCUT + (tkn & 1023));
        } else {
          crow = (size_t)sv;
        }
      } else {
        crow = (size_t)grow;
      }
      #pragma unroll
      for (int nf = 0; nf < NFR; ++nf) {
        const int gcol = nt * BN_ + wn * BNW + nf * 16 + lr;
        float v = acc[mf][nf][jj] + biase[gcol];
        if (MODE == 0 || MODE == 2) {
          ((ushort_t*)C)[crow * (size_t)ldc + gcol] = f2bf(gelu_tanh(v));
        } else if (MODE == 1) {
          ((float*)C)[crow * (size_t)ldc + gcol] = v;
        } else {
          // fused combine: out += LAM * gate * (acc + be2)
          atomicAdd(&((float*)C)[crow * (size_t)ldc + gcol], 0.5f * gt * v);
        }
      }
    }
  }
  #undef STAGE_A
  #undef STAGE_B
  #undef MFMA_QUAD
  #undef PH_SYNC_MFMA
}

// ---------------- workspace layout (bytes) ----------------
#define WS_XB    ((size_t)0)           // 16777216   xb bf16 [8192][1024]
#define WS_W1T   ((size_t)16777216)    //  8388608   W1^T bf16 [4096][1024]
#define WS_W2T   ((size_t)25165824)    //  8388608   W2^T bf16 [1024][4096]
#define WS_WE1T  ((size_t)33554432)    // 16777216   We1^T bf16 [8][1024][1024]
#define WS_WE2T  ((size_t)50331648)    // 16777216   We2^T bf16 [8][1024][1024]
#define WS_H1    ((size_t)67108864)    // 67108864   h1 bf16 [8192][4096]
#define WS_HS    ((size_t)134217728)   // 16777216   h_slot bf16 [8192][1024]
#define WS_CNT   ((size_t)184549376)   // 256        cnt int[8]
#define WS_SLOT  ((size_t)184549632)   // 131072     slots int[8][4096]
#define WS_GSV   ((size_t)184680704)   // 32768      gate per slot fp32[8192]

extern "C" void kernel_launch(void* const* d_in, const int* in_sizes, int n_in,
                              void* d_out, int out_size, void* d_ws, size_t ws_size,
                              hipStream_t stream) {
  const float* x   = (const float*)d_in[0];
  const float* W1  = (const float*)d_in[1];
  const float* b1  = (const float*)d_in[2];
  const float* W2  = (const float*)d_in[3];
  const float* b2  = (const float*)d_in[4];
  const float* Wg  = (const float*)d_in[5];
  const float* We1 = (const float*)d_in[6];
  const float* be1 = (const float*)d_in[7];
  const float* We2 = (const float*)d_in[8];
  const float* be2 = (const float*)d_in[9];
  float* out = (float*)d_out;

  char* ws = (char*)d_ws;
  ushort_t* xb   = (ushort_t*)(ws + WS_XB);
  ushort_t* W1t  = (ushort_t*)(ws + WS_W1T);
  ushort_t* W2t  = (ushort_t*)(ws + WS_W2T);
  ushort_t* We1t = (ushort_t*)(ws + WS_WE1T);
  ushort_t* We2t = (ushort_t*)(ws + WS_WE2T);
  ushort_t* h1   = (ushort_t*)(ws + WS_H1);
  ushort_t* hs   = (ushort_t*)(ws + WS_HS);
  int*      cnt  = (int*)(ws + WS_CNT);
  int*      slots= (int*)(ws + WS_SLOT);
  float*    gsv  = (float*)(ws + WS_GSV);

  // opt-in to >64KB dynamic LDS for the GEMM instantiations
  hipFuncSetAttribute((const void*)gemm8_k<0,256,256,2,4>, hipFuncAttributeMaxDynamicSharedMemorySize, 131072);
  hipFuncSetAttribute((const void*)gemm8_k<1,256,128,4,2>, hipFuncAttributeMaxDynamicSharedMemorySize, 98304);
  hipFuncSetAttribute((const void*)gemm8_k<2,256,128,4,2>, hipFuncAttributeMaxDynamicSharedMemorySize, 98304);
  hipFuncSetAttribute((const void*)gemm8_k<3,256,128,4,2>, hipFuncAttributeMaxDynamicSharedMemorySize, 98304);

  hipMemsetAsync(cnt, 0, 8 * sizeof(int), stream);

  // casts / transposes
  cast4_k<<<NTOK * Dd / 4 / 256, 256, 0, stream>>>(x, xb, NTOK * Dd / 4);
  tcast_k<<<dim3(DFFd / 32, Dd / 32, 1), 256, 0, stream>>>(W1, W1t, Dd, DFFd);
  tcast_k<<<dim3(Dd / 32, DFFd / 32, 1), 256, 0, stream>>>(W2, W2t, DFFd, Dd);
  tcast_k<<<dim3(DFEd / 32, Dd / 32, Ee), 256, 0, stream>>>(We1, We1t, Dd, DFEd);
  tcast_k<<<dim3(Dd / 32, DFEd / 32, Ee), 256, 0, stream>>>(We2, We2t, DFEd, Dd);

  // router
  router_k<<<NMOE / 4, 256, 0, stream>>>(x, Wg, cnt, slots, gsv);

  // FFN1: h1 = gelu(xb @ W1 + b1)    M=8192 N=4096 K=1024  (256x256 tiles, 512 blocks)
  gemm8_k<0,256,256,2,4><<<dim3(512), 512, 131072, stream>>>(
      xb, W1t, b1, h1, NTOK, Dd, DFFd, DFFd / 256, DFFd, nullptr, nullptr, nullptr);
  // MoE1: h_slot = gelu(gather(xb) @ We1[e] + be1[e])   (256x128 tiles)
  gemm8_k<2,256,128,4,2><<<dim3(DFEd / 128, MAXSLOT / 256, Ee), 512, 98304, stream>>>(
      xb, We1t, be1, hs, 0, Dd, DFEd, 0, DFEd, cnt, slots, gsv);
  // FFN2: out = h1 @ W2 + b2         M=8192 N=1024 K=4096  (256x128 tiles, 256 blocks)
  gemm8_k<1,256,128,4,2><<<dim3(256), 512, 98304, stream>>>(
      h1, W2t, b2, out, NTOK, DFFd, Dd, Dd / 128, Dd, nullptr, nullptr, nullptr);
  // MoE2 (+fused combine): out += LAM * gate * (h_slot @ We2[e] + be2[e])
  gemm8_k<3,256,128,4,2><<<dim3(Dd / 128, MAXSLOT / 256, Ee), 512, 98304, stream>>>(
      hs, We2t, be2, out, 0, DFEd, Dd, 0, Dd, cnt, slots, gsv);
}

// Round 6
// 428.325 us; speedup vs baseline: 1.1242x; 1.1242x over previous
//
#include <hip/hip_runtime.h>
#include <hip/hip_bf16.h>
#include <cstdint>
#include <cstddef>

typedef unsigned short ushort_t;
typedef __bf16 bf16x8v __attribute__((ext_vector_type(8)));
typedef float f32x4 __attribute__((ext_vector_type(4)));

// Problem constants (from reference setup_inputs)
#define Bsz 4
#define Sseq 2048
#define Dd 1024
#define DFFd 4096
#define Ee 8
#define DFEd 1024
#define IDCUT 1024          // id = S//2
#define NTOK (Bsz*Sseq)     // 8192
#define NMOE (Bsz*(Sseq-IDCUT)) // 4096 MoE tokens
#define MAXSLOT 4096        // max slots per expert (observed ~1024, 4x headroom)

__device__ __forceinline__ ushort_t f2bf(float f) {
  unsigned u = __float_as_uint(f);
  u += 0x7fffu + ((u >> 16) & 1u);       // round-to-nearest-even
  return (ushort_t)(u >> 16);
}

__device__ __forceinline__ float gelu_tanh(float x) {
  float x3 = x * x * x;
  float t = tanhf(0.7978845608028654f * (x + 0.044715f * x3));
  return 0.5f * x * (1.0f + t);
}

__device__ __forceinline__ void gload_lds16(const void* g, void* l) {
  __builtin_amdgcn_global_load_lds(
      (const __attribute__((address_space(1))) void*)g,
      (__attribute__((address_space(3))) void*)l,
      16, 0, 0);
}

// ---------------- cast x fp32 -> bf16 (straight) ----------------
__global__ void cast4_k(const float* __restrict__ in, ushort_t* __restrict__ out, int n4) {
  int i = blockIdx.x * 256 + threadIdx.x;
  if (i >= n4) return;
  const float4 v = ((const float4*)in)[i];
  ushort4 o;
  o.x = f2bf(v.x); o.y = f2bf(v.y); o.z = f2bf(v.z); o.w = f2bf(v.w);
  ((ushort4*)out)[i] = o;
}

// ---------------- transpose-cast: in [R][C] fp32 -> out [C][R] bf16, batched over z ----------------
__global__ void tcast_k(const float* __restrict__ in, ushort_t* __restrict__ out, int R, int C) {
  __shared__ float tile[32][33];
  const size_t base = (size_t)blockIdx.z * (size_t)R * (size_t)C;
  in += base; out += base;
  int tx = threadIdx.x & 31, ty = threadIdx.x >> 5;   // 32 x 8
  int c = blockIdx.x * 32 + tx;
  #pragma unroll
  for (int i = 0; i < 32; i += 8) {
    int r = blockIdx.y * 32 + ty + i;
    tile[ty + i][tx] = in[(size_t)r * C + c];
  }
  __syncthreads();
  int rr = blockIdx.y * 32 + tx;
  #pragma unroll
  for (int i = 0; i < 32; i += 8) {
    int cc = blockIdx.x * 32 + ty + i;
    out[(size_t)cc * R + rr] = f2bf(tile[tx][ty + i]);
  }
}

// ---------------- router: top-2 gates + per-expert slot lists ----------------
__global__ void router_k(const float* __restrict__ x, const float* __restrict__ Wg,
                         int* __restrict__ cnt, int* __restrict__ slots,
                         float* __restrict__ gsv) {
  int t = blockIdx.x * 4 + (threadIdx.x >> 6);   // one wave per MoE token
  int lane = threadIdx.x & 63;
  int b = t >> 10;
  int s = (t & 1023) + IDCUT;
  const float* xr = x + ((size_t)b * Sseq + s) * Dd;
  float acc[8] = {0.f,0.f,0.f,0.f,0.f,0.f,0.f,0.f};
  for (int k = lane; k < Dd; k += 64) {
    float xv = xr[k];
    const float* wr = Wg + (size_t)k * Ee;
    #pragma unroll
    for (int e8 = 0; e8 < 8; ++e8) acc[e8] += xv * wr[e8];
  }
  #pragma unroll
  for (int off = 32; off > 0; off >>= 1) {
    #pragma unroll
    for (int e8 = 0; e8 < 8; ++e8) acc[e8] += __shfl_xor(acc[e8], off);
  }
  if (lane == 0) {
    int e0 = 0; float v0 = acc[0];
    #pragma unroll
    for (int e8 = 1; e8 < 8; ++e8) if (acc[e8] > v0) { v0 = acc[e8]; e0 = e8; }
    int e1 = -1; float v1 = -3.4e38f;
    #pragma unroll
    for (int e8 = 0; e8 < 8; ++e8) if (e8 != e0 && acc[e8] > v1) { v1 = acc[e8]; e1 = e8; }
    float g0 = 1.0f / (1.0f + expf(v1 - v0));   // = p0/(p0+p1), exact via softmax monotonicity
    float g1 = 1.0f - g0;
    int p0 = atomicAdd(&cnt[e0], 1);
    slots[e0 * MAXSLOT + p0] = t * 2;
    int p1 = atomicAdd(&cnt[e1], 1);
    slots[e1 * MAXSLOT + p1] = t * 2 + 1;
    gsv[t * 2] = g0;
    gsv[t * 2 + 1] = g1;
  }
}

// ================= 128x128 BK=64 m97-structure tile (round 6) =================
// 4 waves (2x2 of 64x64), single-buffer 32KB LDS -> ~3 blocks/CU implicit
// overlap (m114 regime). 8-way XOR swizzle: source col pre-permuted
// (slot^row&7), read XOR'd back; 128B rows = 8 slots -> full spread.
// MODE 0: FFN1  epi gelu->bf16 | 1: FFN2 epi ->fp32 | 2: MoE1 gather-gelu->bf16
// MODE 3: MoE2 gather, epi atomicAdd(out, LAM*gate*(acc+be2))
template<int MODE>
__device__ __forceinline__ void gemm_tile(
    int nt, int mt, int e,
    const ushort_t* __restrict__ A, const ushort_t* __restrict__ Bt,
    const float* __restrict__ bias, void* __restrict__ C,
    int M, int K, int N, int ldc,
    const int* __restrict__ cnt, const int* __restrict__ slots,
    const float* __restrict__ gates,
    ushort_t* Al, ushort_t* Bl)
{
  int rows = M;
  const int* slist = nullptr;
  if (MODE >= 2) {
    rows = cnt[e];
    if (mt * 128 >= rows) return;
    slist = slots + e * MAXSLOT;
  }
  const ushort_t* Bte = (MODE >= 2) ? (Bt + (size_t)e * (size_t)K * (size_t)N) : Bt;
  const float* biase = (MODE >= 2) ? (bias + e * N) : bias;

  const int tid  = threadIdx.x;
  const int lane = tid & 63;
  const int wid  = tid >> 6;
  const int wr   = wid >> 1, wc = wid & 1;
  const int lr   = lane & 15;
  const int lg   = lane >> 4;
  const int swz7 = lane & 7;   // == row&7 on the read side (rows stride 16)

  // --- staging source pointers: 4 slots/thread per matrix, pre-swizzled col ---
  const ushort_t* gA[4];
  const ushort_t* gB[4];
  #pragma unroll
  for (int j = 0; j < 4; ++j) {
    int tt = j * 256 + tid;
    int rl = tt >> 3, slot = tt & 7;
    int col8 = slot ^ (rl & 7);
    int grow = mt * 128 + rl;
    size_t rowoff;
    if (MODE < 2) {
      rowoff = (size_t)grow;
    } else {
      int idx = grow > rows - 1 ? rows - 1 : grow;
      int sv = slist[idx];
      if (MODE == 2) { int t = sv >> 1; rowoff = (size_t)((t >> 10) * Sseq + IDCUT + (t & 1023)); }
      else           { rowoff = (size_t)sv; }
    }
    gA[j] = A + rowoff * (size_t)K + col8 * 8;
    gB[j] = Bte + (size_t)(nt * 128 + rl) * (size_t)K + col8 * 8;
  }

  f32x4 acc[4][4];
  const f32x4 vzero = {0.f, 0.f, 0.f, 0.f};
  #pragma unroll
  for (int m = 0; m < 4; ++m)
    #pragma unroll
    for (int n = 0; n < 4; ++n) acc[m][n] = vzero;

  // per-lane swizzled read offsets (bytes), per-frag part is compile-time imm
  const unsigned aRow = (unsigned)((wr * 64 + lr) * 128);
  const unsigned bRow = (unsigned)((wc * 64 + lr) * 128);
  const unsigned s0 = (unsigned)((lg ^ swz7) << 4);        // ks=0 slot
  const unsigned s1 = (unsigned)(((4 + lg) ^ swz7) << 4);  // ks=1 slot

  for (int k0 = 0; k0 < K; k0 += 64) {
    __syncthreads();
    #pragma unroll
    for (int j = 0; j < 4; ++j)
      gload_lds16(gA[j] + k0, (void*)((char*)Al + (j * 256 + wid * 64) * 16));
    #pragma unroll
    for (int j = 0; j < 4; ++j)
      gload_lds16(gB[j] + k0, (void*)((char*)Bl + (j * 256 + wid * 64) * 16));
    __syncthreads();   // compiler inserts vmcnt(0) drain here (m97 pattern)

    bf16x8v af[4][2], bf[4][2];
    #pragma unroll
    for (int mi = 0; mi < 4; ++mi) {
      af[mi][0] = *(const bf16x8v*)((const char*)Al + aRow + mi * 2048 + s0);
      af[mi][1] = *(const bf16x8v*)((const char*)Al + aRow + mi * 2048 + s1);
    }
    #pragma unroll
    for (int ni = 0; ni < 4; ++ni) {
      bf[ni][0] = *(const bf16x8v*)((const char*)Bl + bRow + ni * 2048 + s0);
      bf[ni][1] = *(const bf16x8v*)((const char*)Bl + bRow + ni * 2048 + s1);
    }
    #pragma unroll
    for (int ks = 0; ks < 2; ++ks)
      #pragma unroll
      for (int mi = 0; mi < 4; ++mi)
        #pragma unroll
        for (int ni = 0; ni < 4; ++ni)
          acc[mi][ni] = __builtin_amdgcn_mfma_f32_16x16x32_bf16(
              af[mi][ks], bf[ni][ks], acc[mi][ni], 0, 0, 0);
  }

  // --- epilogue: C/D layout col = lane&15, row = (lane>>4)*4 + jj ---
  #pragma unroll
  for (int mf = 0; mf < 4; ++mf) {
    #pragma unroll
    for (int jj = 0; jj < 4; ++jj) {
      const int lrow = wr * 64 + mf * 16 + lg * 4 + jj;
      const int grow = mt * 128 + lrow;
      size_t crow; float gt = 0.f;
      if (MODE >= 2) {
        if (grow >= rows) continue;
        int sv = slist[grow];
        if (MODE == 3) {
          gt = gates[sv];
          int tkn = sv >> 1;
          crow = (size_t)((tkn >> 10) * Sseq + IDCUT + (tkn & 1023));
        } else {
          crow = (size_t)sv;
        }
      } else {
        crow = (size_t)grow;
      }
      #pragma unroll
      for (int nf = 0; nf < 4; ++nf) {
        const int gcol = nt * 128 + wc * 64 + nf * 16 + lr;
        float v = acc[mf][nf][jj] + biase[gcol];
        if (MODE == 0 || MODE == 2) {
          ((ushort_t*)C)[crow * (size_t)ldc + gcol] = f2bf(gelu_tanh(v));
        } else if (MODE == 1) {
          ((float*)C)[crow * (size_t)ldc + gcol] = v;
        } else {
          atomicAdd(&((float*)C)[crow * (size_t)ldc + gcol], 0.5f * gt * v);
        }
      }
    }
  }
}

// FFN1 (2048 blocks, XCD/L2 map) + MoE1 (2048 blocks) merged
__global__ __launch_bounds__(256, 2) void fused1_k(
    const ushort_t* __restrict__ xb,
    const ushort_t* __restrict__ W1t, const float* __restrict__ b1, ushort_t* __restrict__ h1,
    const ushort_t* __restrict__ We1t, const float* __restrict__ be1, ushort_t* __restrict__ hs,
    const int* __restrict__ cnt, const int* __restrict__ slots)
{
  __shared__ ushort_t Al[128 * 64];
  __shared__ ushort_t Bl[128 * 64];
  int wg = blockIdx.x;
  if (wg < 2048) {
    // FFN1: xcd owns 4 nt-columns (B-panels 1MB, L2-resident); mt-major inside
    int xcd = wg & 7, idx = wg >> 3;
    int mt = idx >> 2, nt = xcd * 4 + (idx & 3);
    gemm_tile<0>(nt, mt, 0, xb, W1t, b1, (void*)h1, NTOK, Dd, DFFd, DFFd,
                 nullptr, nullptr, nullptr, Al, Bl);
  } else {
    int i = wg - 2048;
    int e = i >> 8, rem = i & 255;
    int mt = rem >> 3, nt = rem & 7;
    gemm_tile<2>(nt, mt, e, xb, We1t, be1, (void*)hs, 0, Dd, DFEd, DFEd,
                 cnt, slots, nullptr, Al, Bl);
  }
}

// FFN2: 512 blocks, xcd owns one nt-column
__global__ __launch_bounds__(256, 2) void ffn2_k(
    const ushort_t* __restrict__ h1,
    const ushort_t* __restrict__ W2t, const float* __restrict__ b2,
    float* __restrict__ out)
{
  __shared__ ushort_t Al[128 * 64];
  __shared__ ushort_t Bl[128 * 64];
  int wg = blockIdx.x;
  int nt = wg & 7, mt = wg >> 3;
  gemm_tile<1>(nt, mt, 0, h1, W2t, b2, (void*)out, NTOK, DFFd, Dd, Dd,
               nullptr, nullptr, nullptr, Al, Bl);
}

// MoE2 (+fused combine): out += LAM*gate*(hs @ We2 + be2)
__global__ __launch_bounds__(256, 2) void moe2_k(
    const ushort_t* __restrict__ hs,
    const ushort_t* __restrict__ We2t, const float* __restrict__ be2,
    float* __restrict__ out,
    const int* __restrict__ cnt, const int* __restrict__ slots,
    const float* __restrict__ gsv)
{
  __shared__ ushort_t Al[128 * 64];
  __shared__ ushort_t Bl[128 * 64];
  int wg = blockIdx.x;
  int e = wg >> 8, rem = wg & 255;
  int mt = rem >> 3, nt = rem & 7;
  gemm_tile<3>(nt, mt, e, hs, We2t, be2, (void*)out, 0, DFEd, Dd, Dd,
               cnt, slots, gsv, Al, Bl);
}

// ---------------- workspace layout (bytes) ----------------
#define WS_XB    ((size_t)0)           // 16777216   xb bf16 [8192][1024]
#define WS_W1T   ((size_t)16777216)    //  8388608   W1^T bf16 [4096][1024]
#define WS_W2T   ((size_t)25165824)    //  8388608   W2^T bf16 [1024][4096]
#define WS_WE1T  ((size_t)33554432)    // 16777216   We1^T bf16 [8][1024][1024]
#define WS_WE2T  ((size_t)50331648)    // 16777216   We2^T bf16 [8][1024][1024]
#define WS_H1    ((size_t)67108864)    // 67108864   h1 bf16 [8192][4096]
#define WS_HS    ((size_t)134217728)   // 16777216   h_slot bf16 [8192][1024]
#define WS_CNT   ((size_t)184549376)   // 256        cnt int[8]
#define WS_SLOT  ((size_t)184549632)   // 131072     slots int[8][4096]
#define WS_GSV   ((size_t)184680704)   // 32768      gate per slot fp32[8192]

extern "C" void kernel_launch(void* const* d_in, const int* in_sizes, int n_in,
                              void* d_out, int out_size, void* d_ws, size_t ws_size,
                              hipStream_t stream) {
  const float* x   = (const float*)d_in[0];
  const float* W1  = (const float*)d_in[1];
  const float* b1  = (const float*)d_in[2];
  const float* W2  = (const float*)d_in[3];
  const float* b2  = (const float*)d_in[4];
  const float* Wg  = (const float*)d_in[5];
  const float* We1 = (const float*)d_in[6];
  const float* be1 = (const float*)d_in[7];
  const float* We2 = (const float*)d_in[8];
  const float* be2 = (const float*)d_in[9];
  float* out = (float*)d_out;

  char* ws = (char*)d_ws;
  ushort_t* xb   = (ushort_t*)(ws + WS_XB);
  ushort_t* W1t  = (ushort_t*)(ws + WS_W1T);
  ushort_t* W2t  = (ushort_t*)(ws + WS_W2T);
  ushort_t* We1t = (ushort_t*)(ws + WS_WE1T);
  ushort_t* We2t = (ushort_t*)(ws + WS_WE2T);
  ushort_t* h1   = (ushort_t*)(ws + WS_H1);
  ushort_t* hs   = (ushort_t*)(ws + WS_HS);
  int*      cnt  = (int*)(ws + WS_CNT);
  int*      slots= (int*)(ws + WS_SLOT);
  float*    gsv  = (float*)(ws + WS_GSV);

  hipMemsetAsync(cnt, 0, 8 * sizeof(int), stream);

  // casts / transposes
  cast4_k<<<NTOK * Dd / 4 / 256, 256, 0, stream>>>(x, xb, NTOK * Dd / 4);
  tcast_k<<<dim3(DFFd / 32, Dd / 32, 1), 256, 0, stream>>>(W1, W1t, Dd, DFFd);
  tcast_k<<<dim3(Dd / 32, DFFd / 32, 1), 256, 0, stream>>>(W2, W2t, DFFd, Dd);
  tcast_k<<<dim3(DFEd / 32, Dd / 32, Ee), 256, 0, stream>>>(We1, We1t, Dd, DFEd);
  tcast_k<<<dim3(Dd / 32, DFEd / 32, Ee), 256, 0, stream>>>(We2, We2t, DFEd, Dd);

  // router
  router_k<<<NMOE / 4, 256, 0, stream>>>(x, Wg, cnt, slots, gsv);

  // FFN1 + MoE1 (independent, both read xb) in one launch
  fused1_k<<<dim3(4096), 256, 0, stream>>>(xb, W1t, b1, h1, We1t, be1, hs, cnt, slots);
  // FFN2: out = h1 @ W2 + b2
  ffn2_k<<<dim3(512), 256, 0, stream>>>(h1, W2t, b2, out);
  // MoE2 (+fused combine)
  moe2_k<<<dim3(2048), 256, 0, stream>>>(hs, We2t, be2, out, cnt, slots, gsv);
}